// Round 2
// baseline (2133.897 us; speedup 1.0000x reference)
//
#include <hip/hip_runtime.h>
#include <math.h>

#define Tdim 2048
#define HIDd 1024
#define NHd 16
#define NCOL 4096         // NH*16*16
#define Cn 64             // chunks per sequence
#define Ln 32             // chunk length (Cn*Ln == Tdim)

typedef _Float16 half4v __attribute__((ext_vector_type(4)));

__device__ inline float4 ld4f(const float* p) { return *(const float4*)p; }
__device__ inline float4 ld4f(const _Float16* p) {
    half4v h = *(const half4v*)p;
    return make_float4((float)h[0], (float)h[1], (float)h[2], (float)h[3]);
}
__device__ inline void st4f(float* p, float4 v) { *(float4*)p = v; }
__device__ inline void st4f(_Float16* p, float4 v) {
    half4v h;
    h[0] = (_Float16)v.x; h[1] = (_Float16)v.y; h[2] = (_Float16)v.z; h[3] = (_Float16)v.w;
    *(half4v*)p = h;
}

// ---------------- GEMM1: m = hs @ W_mat + b_mat, scattered to (seq_local,t,256) ----------
template <typename T>
__global__ __launch_bounds__(256) void gemm1_kernel(const float* __restrict__ A,
                                                    const float* __restrict__ W,
                                                    const float* __restrict__ bias,
                                                    T* __restrict__ Mout, int row0)
{
    __shared__ float As[16][128];
    __shared__ float Bs[16][128];
    const int tid = threadIdx.x;
    const int r0 = blockIdx.y * 128;          // local row tile
    const int c0 = blockIdx.x * 128;
    const int ty = tid >> 4, tx = tid & 15;
    const int a_row = tid >> 1, a_col = (tid & 1) * 8;
    const int b_row = tid >> 4, b_col = (tid & 15) * 8;

    float acc[8][8];
#pragma unroll
    for (int i = 0; i < 8; ++i)
#pragma unroll
        for (int j = 0; j < 8; ++j) acc[i][j] = 0.f;

    const float* Aptr = A + (size_t)(row0 + r0 + a_row) * HIDd + a_col;
    const float* Wptr = W + (size_t)b_row * NCOL + c0 + b_col;

    for (int kk = 0; kk < HIDd; kk += 16) {
        float4 av0 = *(const float4*)(Aptr + kk);
        float4 av1 = *(const float4*)(Aptr + kk + 4);
        float4 bv0 = *(const float4*)(Wptr + (size_t)kk * NCOL);
        float4 bv1 = *(const float4*)(Wptr + (size_t)kk * NCOL + 4);
        __syncthreads();
        As[a_col + 0][a_row] = av0.x;
        As[a_col + 1][a_row] = av0.y;
        As[a_col + 2][a_row] = av0.z;
        As[a_col + 3][a_row] = av0.w;
        As[a_col + 4][a_row] = av1.x;
        As[a_col + 5][a_row] = av1.y;
        As[a_col + 6][a_row] = av1.z;
        As[a_col + 7][a_row] = av1.w;
        *(float4*)&Bs[b_row][b_col]     = bv0;
        *(float4*)&Bs[b_row][b_col + 4] = bv1;
        __syncthreads();
#pragma unroll
        for (int k = 0; k < 16; ++k) {
            float a[8], b[8];
            *(float4*)&a[0] = *(const float4*)&As[k][ty * 8];
            *(float4*)&a[4] = *(const float4*)&As[k][ty * 8 + 4];
            *(float4*)&b[0] = *(const float4*)&Bs[k][tx * 8];
            *(float4*)&b[4] = *(const float4*)&Bs[k][tx * 8 + 4];
#pragma unroll
            for (int i = 0; i < 8; ++i)
#pragma unroll
                for (int j = 0; j < 8; ++j)
                    acc[i][j] = fmaf(a[i], b[j], acc[i][j]);
        }
    }
#pragma unroll
    for (int i = 0; i < 8; ++i) {
        const int r = r0 + ty * 8 + i;        // local row
        const int bbl = r >> 11, t = r & 2047;
#pragma unroll
        for (int jj = 0; jj < 8; jj += 4) {
            const int c = c0 + tx * 8 + jj;
            const int h = c >> 8, e = c & 255;
            float4 v;
            v.x = acc[i][jj + 0] + bias[c + 0];
            v.y = acc[i][jj + 1] + bias[c + 1];
            v.z = acc[i][jj + 2] + bias[c + 2];
            v.w = acc[i][jj + 3] + bias[c + 3];
            st4f(Mout + (((size_t)(bbl * 16 + h) * Tdim + t) * 256 + e), v);
        }
    }
}

// ---------------- Frobenius normalization, in place: m *= 4/(fro+1e-5) ----------------
template <typename T>
__global__ __launch_bounds__(256) void fro_norm_kernel(T* __restrict__ m)
{
    const int lane = threadIdx.x & 63;
    const size_t idx = (size_t)blockIdx.x * 4 + (threadIdx.x >> 6);
    T* p = m + idx * 256 + lane * 4;
    float4 v = ld4f(p);
    float s = v.x * v.x + v.y * v.y + v.z * v.z + v.w * v.w;
#pragma unroll
    for (int off = 1; off < 64; off <<= 1) s += __shfl_xor(s, off);
    const float scale = 4.0f / (sqrtf(s) + 1e-5f);
    v.x *= scale; v.y *= scale; v.z *= scale; v.w *= scale;
    st4f(p, v);
}

// ---------------- Stage A: per-chunk products, both directions, one wave per (seq,chunk) --
template <typename T>
__global__ __launch_bounds__(256) void stageA_kernel(const T* __restrict__ m,
                                                     float* __restrict__ q, int SS)
{
    __shared__ float Msh[4][256];
    const int tid = threadIdx.x;
    const int w = tid >> 6, lane = tid & 63;
    const int chain = blockIdx.x * 4 + w;          // (seq_local, c)
    const int seq = chain >> 6, c = chain & (Cn - 1);
    const int g = lane >> 4, j = lane & 15;

    float qlr[4], qrt[4];
#pragma unroll
    for (int a = 0; a < 4; ++a) {
        const float iv = (4 * g + a == j) ? 1.0f : 0.0f;
        qlr[a] = iv; qrt[a] = iv;
    }
    const T* mp = m + ((size_t)seq * Tdim + c * Ln) * 256 + lane * 4;
    float* sh = &Msh[w][0];

    for (int s = 0; s < Ln; ++s) {
        const float4 mv = ld4f(mp + (size_t)s * 256);
        __syncthreads();
        *(float4*)&sh[lane * 4] = mv;
        __syncthreads();
        float qn[4]  = {0.f, 0.f, 0.f, 0.f};
        float qtn[4] = {0.f, 0.f, 0.f, 0.f};
#pragma unroll
        for (int kcl = 0; kcl < 4; ++kcl) {
            const int kc = (kcl + g) & 3;          // group-rotated: bank-conflict-free
            const float4 row0 = *(const float4*)&sh[(4 * g + 0) * 16 + 4 * kc];
            const float4 row1 = *(const float4*)&sh[(4 * g + 1) * 16 + 4 * kc];
            const float4 row2 = *(const float4*)&sh[(4 * g + 2) * 16 + 4 * kc];
            const float4 row3 = *(const float4*)&sh[(4 * g + 3) * 16 + 4 * kc];
#pragma unroll
            for (int bk = 0; bk < 4; ++bk) {
                const int k = 4 * kc + bk;
                const int src = (kc << 4) | j;
                const float qk  = __shfl(qlr[bk], src);   // Q[k][j]
                const float qtk = __shfl(qrt[bk], src);   // QrlT[k][j]
                const float4 mc = *(const float4*)&sh[k * 16 + 4 * g];
                qn[0] = fmaf((&row0.x)[bk], qk, qn[0]);
                qn[1] = fmaf((&row1.x)[bk], qk, qn[1]);
                qn[2] = fmaf((&row2.x)[bk], qk, qn[2]);
                qn[3] = fmaf((&row3.x)[bk], qk, qn[3]);
                qtn[0] = fmaf(mc.x, qtk, qtn[0]);
                qtn[1] = fmaf(mc.y, qtk, qtn[1]);
                qtn[2] = fmaf(mc.z, qtk, qtn[2]);
                qtn[3] = fmaf(mc.w, qtk, qtn[3]);
            }
        }
#pragma unroll
        for (int a = 0; a < 4; ++a) { qlr[a] = qn[a]; qrt[a] = qtn[a]; }
    }
    // normalize both chunk products (positive scale: projectively legal)
    float ss = qlr[0]*qlr[0] + qlr[1]*qlr[1] + qlr[2]*qlr[2] + qlr[3]*qlr[3];
    float st = qrt[0]*qrt[0] + qrt[1]*qrt[1] + qrt[2]*qrt[2] + qrt[3]*qrt[3];
#pragma unroll
    for (int off = 1; off < 64; off <<= 1) { ss += __shfl_xor(ss, off); st += __shfl_xor(st, off); }
    const float sl = 1.0f / (sqrtf(ss) + 1e-30f);
    const float sr = 1.0f / (sqrtf(st) + 1e-30f);
    float* qlr_out = q + ((size_t)seq * Cn + c) * 256;
    float* qrl_out = q + ((size_t)(SS + seq) * Cn + c) * 256;
#pragma unroll
    for (int a = 0; a < 4; ++a) qlr_out[(4 * g + a) * 16 + j] = qlr[a] * sl;
    float4 qv; qv.x = qrt[0]*sr; qv.y = qrt[1]*sr; qv.z = qrt[2]*sr; qv.w = qrt[3]*sr;
    *(float4*)(qrl_out + j * 16 + 4 * g) = qv;     // QrlT -> Qrl transposed store
}

// ---------------- Stage B: cross-chunk vector propagation --------------------------------
__global__ __launch_bounds__(64) void stageB_kernel(const float* __restrict__ q,
                                                    float* __restrict__ vs, int SS)
{
    const int lane = threadIdx.x & 63;
    const int i = lane & 15;
    const int chain = blockIdx.x;                  // 0 .. 2*SS-1
    const int dir = (chain >= SS) ? 1 : 0;
    const int seq = chain - dir * SS;
    const float* qb = q + (size_t)(dir * SS + seq) * Cn * 256;
    float* vb = vs + (size_t)(dir * SS + seq) * Cn * 16;

    float myw = (i == 0) ? 1.0f : 0.0f;
    float wv[16];
#pragma unroll
    for (int k2 = 0; k2 < 16; ++k2) wv[k2] = (k2 == 0) ? 1.0f : 0.0f;

    for (int s = 0; s < Cn; ++s) {
        const int cc = dir ? (Cn - 1 - s) : s;
        vb[cc * 16 + i] = myw;                     // start vector for chunk cc
        const float* Qp = qb + (size_t)cc * 256 + i * 16;
        const float4 q0 = *(const float4*)(Qp + 0);
        const float4 q1 = *(const float4*)(Qp + 4);
        const float4 q2 = *(const float4*)(Qp + 8);
        const float4 q3 = *(const float4*)(Qp + 12);
        float nv = q0.x*wv[0] + q0.y*wv[1] + q0.z*wv[2] + q0.w*wv[3]
                 + q1.x*wv[4] + q1.y*wv[5] + q1.z*wv[6] + q1.w*wv[7]
                 + q2.x*wv[8] + q2.y*wv[9] + q2.z*wv[10] + q2.w*wv[11]
                 + q3.x*wv[12] + q3.y*wv[13] + q3.z*wv[14] + q3.w*wv[15];
        float s2 = nv * nv;
        s2 += __shfl_xor(s2, 1); s2 += __shfl_xor(s2, 2);
        s2 += __shfl_xor(s2, 4); s2 += __shfl_xor(s2, 8);
        const float wn = nv / (sqrtf(s2) + 1e-20f);
        myw = wn;
#pragma unroll
        for (int k2 = 0; k2 < 16; ++k2) wv[k2] = __shfl(wn, (lane & 48) | k2);
    }
}

// ---------------- Stage C: per-step history with exact reference normalization ------------
template <typename T>
__global__ __launch_bounds__(256) void stageC_kernel(const T* __restrict__ m,
                                                     const float* __restrict__ vs,
                                                     float* __restrict__ x, int SS)
{
    const int tid = threadIdx.x;
    const int lane = tid & 63;
    const int i = lane & 15;
    const int chain = blockIdx.x * 16 + (tid >> 4); // 0 .. 2*SS*Cn-1
    const int dir = chain & 1;
    const int sc = chain >> 1;
    const int c = sc & (Cn - 1), seq = sc >> 6;     // seq_local < SS
    const int bbl = seq >> 4, h = seq & 15;

    const float* vp = vs + ((size_t)(dir * SS + seq) * Cn + c) * 16;
    float vv[16];
#pragma unroll
    for (int k2 = 0; k2 < 16; ++k2) vv[k2] = vp[k2];

    const int t0 = c * Ln;
    for (int s = 0; s < Ln; ++s) {
        const int t = dir ? (t0 + Ln - 1 - s) : (t0 + s);
        const T* Mp = m + ((size_t)seq * Tdim + t) * 256 + i * 16;
        const float4 r0 = ld4f(Mp + 0);
        const float4 r1 = ld4f(Mp + 4);
        const float4 r2 = ld4f(Mp + 8);
        const float4 r3 = ld4f(Mp + 12);
        float nv = r0.x*vv[0] + r0.y*vv[1] + r0.z*vv[2] + r0.w*vv[3]
                 + r1.x*vv[4] + r1.y*vv[5] + r1.z*vv[6] + r1.w*vv[7]
                 + r2.x*vv[8] + r2.y*vv[9] + r2.z*vv[10] + r2.w*vv[11]
                 + r3.x*vv[12] + r3.y*vv[13] + r3.z*vv[14] + r3.w*vv[15];
        float s2 = nv * nv;
        s2 += __shfl_xor(s2, 1); s2 += __shfl_xor(s2, 2);
        s2 += __shfl_xor(s2, 4); s2 += __shfl_xor(s2, 8);
        const float vn = nv / (sqrtf(s2) + 1e-6f);     // reference VEC_EPS semantics
        x[(((size_t)bbl * Tdim + t) * NHd + h) * 32 + dir * 16 + i] = vn;
#pragma unroll
        for (int k2 = 0; k2 < 16; ++k2) vv[k2] = __shfl(vn, (lane & 48) | k2);
    }
}

// ---------------- GEMM2: out = gelu(x @ W_out + b_out), exact erf gelu --------------------
__global__ __launch_bounds__(256) void gemm2_kernel(const float* __restrict__ A,
                                                    const float* __restrict__ W,
                                                    const float* __restrict__ bias,
                                                    float* __restrict__ out, int row0)
{
    __shared__ float As[16][128];
    __shared__ float Bs[16][128];
    const int tid = threadIdx.x;
    const int r0 = blockIdx.y * 128;               // local row tile
    const int c0 = blockIdx.x * 128;
    const int ty = tid >> 4, tx = tid & 15;
    const int a_row = tid >> 1, a_col = (tid & 1) * 8;
    const int b_row = tid >> 4, b_col = (tid & 15) * 8;

    float acc[8][8];
#pragma unroll
    for (int i = 0; i < 8; ++i)
#pragma unroll
        for (int j = 0; j < 8; ++j) acc[i][j] = 0.f;

    const float* Aptr = A + (size_t)(r0 + a_row) * 512 + a_col;
    const float* Wptr = W + (size_t)b_row * 1024 + c0 + b_col;

    for (int kk = 0; kk < 512; kk += 16) {
        float4 av0 = *(const float4*)(Aptr + kk);
        float4 av1 = *(const float4*)(Aptr + kk + 4);
        float4 bv0 = *(const float4*)(Wptr + (size_t)kk * 1024);
        float4 bv1 = *(const float4*)(Wptr + (size_t)kk * 1024 + 4);
        __syncthreads();
        As[a_col + 0][a_row] = av0.x;
        As[a_col + 1][a_row] = av0.y;
        As[a_col + 2][a_row] = av0.z;
        As[a_col + 3][a_row] = av0.w;
        As[a_col + 4][a_row] = av1.x;
        As[a_col + 5][a_row] = av1.y;
        As[a_col + 6][a_row] = av1.z;
        As[a_col + 7][a_row] = av1.w;
        *(float4*)&Bs[b_row][b_col]     = bv0;
        *(float4*)&Bs[b_row][b_col + 4] = bv1;
        __syncthreads();
#pragma unroll
        for (int k = 0; k < 16; ++k) {
            float a[8], b[8];
            *(float4*)&a[0] = *(const float4*)&As[k][ty * 8];
            *(float4*)&a[4] = *(const float4*)&As[k][ty * 8 + 4];
            *(float4*)&b[0] = *(const float4*)&Bs[k][tx * 8];
            *(float4*)&b[4] = *(const float4*)&Bs[k][tx * 8 + 4];
#pragma unroll
            for (int i = 0; i < 8; ++i)
#pragma unroll
                for (int j = 0; j < 8; ++j)
                    acc[i][j] = fmaf(a[i], b[j], acc[i][j]);
        }
    }
#pragma unroll
    for (int i = 0; i < 8; ++i) {
        const int r = r0 + ty * 8 + i;
#pragma unroll
        for (int jj = 0; jj < 8; jj += 4) {
            const int c = c0 + tx * 8 + jj;
            float4 v;
            v.x = acc[i][jj + 0] + bias[c + 0];
            v.y = acc[i][jj + 1] + bias[c + 1];
            v.z = acc[i][jj + 2] + bias[c + 2];
            v.w = acc[i][jj + 3] + bias[c + 3];
            v.x = 0.5f * v.x * (1.0f + erff(v.x * 0.70710678118654752f));
            v.y = 0.5f * v.y * (1.0f + erff(v.y * 0.70710678118654752f));
            v.z = 0.5f * v.z * (1.0f + erff(v.z * 0.70710678118654752f));
            v.w = 0.5f * v.w * (1.0f + erff(v.w * 0.70710678118654752f));
            *(float4*)(out + (size_t)(row0 + r) * 1024 + c) = v;
        }
    }
}

// ---------------- host: ws-size-adaptive tiered launch ------------------------------------
template <typename T>
static void run_path(const float* hs, const float* W_mat, const float* b_mat,
                     const float* W_out, const float* b_out, float* out,
                     void* d_ws, int nbb, hipStream_t stream)
{
    const int SS = nbb * 16;                       // sequences per slab
    char* base = (char*)d_ws;
    T*     m  = (T*)base;                                           // nbb*8,388,608 T
    float* qx = (float*)(base + (size_t)nbb * 8388608 * sizeof(T)); // q (2 MiB/bb) / x (4 MiB/bb) aliased
    float* vs = qx + (size_t)nbb * 1048576;                         // nbb*32768 floats

    for (int bb0 = 0; bb0 < 8; bb0 += nbb) {
        const int row0 = bb0 * Tdim;
        gemm1_kernel<T><<<dim3(32, nbb * 16), 256, 0, stream>>>(hs, W_mat, b_mat, m, row0);
        fro_norm_kernel<T><<<nbb * 8192, 256, 0, stream>>>(m);
        stageA_kernel<T><<<nbb * 256, 256, 0, stream>>>(m, qx, SS);
        stageB_kernel<<<nbb * 32, 64, 0, stream>>>(qx, vs, SS);
        stageC_kernel<T><<<nbb * 128, 256, 0, stream>>>(m, vs, qx, SS);   // x aliases q
        gemm2_kernel<<<dim3(8, nbb * 16), 256, 0, stream>>>(qx, W_out, b_out, out, row0);
    }
}

extern "C" void kernel_launch(void* const* d_in, const int* in_sizes, int n_in,
                              void* d_out, int out_size, void* d_ws, size_t ws_size,
                              hipStream_t stream)
{
    const float* hs    = (const float*)d_in[0];
    const float* W_mat = (const float*)d_in[1];
    const float* b_mat = (const float*)d_in[2];
    const float* W_out = (const float*)d_in[3];
    const float* b_out = (const float*)d_in[4];
    float* out = (float*)d_out;

    // per-batch footprint: m + max(q,x) + vs
    const size_t per_f32 = 8388608ull * 4 + 1048576ull * 4 + 32768ull * 4; // 37,879,808 B
    const size_t per_f16 = 8388608ull * 2 + 1048576ull * 4 + 32768ull * 4; // 21,102,592 B

    int nbb;
    if      (ws_size >= 8 * per_f32) nbb = 8;
    else if (ws_size >= 4 * per_f32) nbb = 4;
    else if (ws_size >= 2 * per_f32) nbb = 2;
    else if (ws_size >= 1 * per_f32) nbb = 1;
    else nbb = 0;

    if (nbb > 0) {
        run_path<float>(hs, W_mat, b_mat, W_out, b_out, out, d_ws, nbb, stream);
    } else {
        if      (ws_size >= 8 * per_f16) nbb = 8;
        else if (ws_size >= 4 * per_f16) nbb = 4;
        else if (ws_size >= 2 * per_f16) nbb = 2;
        else                             nbb = 1;   // last resort
        run_path<_Float16>(hs, W_mat, b_mat, W_out, b_out, out, d_ws, nbb, stream);
    }
}

// Round 4
// 1477.789 us; speedup vs baseline: 1.4440x; 1.4440x over previous
//
#include <hip/hip_runtime.h>
#include <math.h>

#define Tdim 2048
#define HIDd 1024
#define NHd 16
#define NCOL 4096         // NH*16*16
#define Cn 64             // chunks per sequence
#define Ln 32             // chunk length (Cn*Ln == Tdim)
#define LSTR 40           // f16 elems per LDS row (80 B): bank-friendly pad

typedef _Float16 f16x8  __attribute__((ext_vector_type(8)));
typedef float    f32x4  __attribute__((ext_vector_type(4)));

// ---------------- W (1024 x 4096 fp32) -> WhT / WlT (4096 x 1024 fp16, lo pre-scaled x1024)
__global__ __launch_bounds__(256) void conv_WT_kernel(const float* __restrict__ W,
                                                      _Float16* __restrict__ WhT,
                                                      _Float16* __restrict__ WlT)
{
    __shared__ float t[32][33];
    const int tx = threadIdx.x & 31, ty = threadIdx.x >> 5;   // ty 0..7
    const int n0 = blockIdx.x * 32, k0 = blockIdx.y * 32;
#pragma unroll
    for (int i = 0; i < 4; ++i)
        t[ty + i * 8][tx] = W[(size_t)(k0 + ty + i * 8) * NCOL + n0 + tx];
    __syncthreads();
#pragma unroll
    for (int i = 0; i < 4; ++i) {
        const float w = t[tx][ty + i * 8];          // W[k0+tx][n0+ty+i*8]
        const _Float16 h = (_Float16)w;
        const size_t o = (size_t)(n0 + ty + i * 8) * HIDd + k0 + tx;
        WhT[o] = h;
        WlT[o] = (_Float16)((w - (float)h) * 1024.0f);   // scaled into f16 normal range
    }
}

// ---------------- GEMM1 (split-f16 MFMA): m = hs @ W_mat + b_mat -> fp32, scattered -------
// A: slab rows x 1024 fp32 row-major;  BhT/BlT: 4096 x 1024 fp16 (W transposed, hi/lo)
__device__ inline void split8(float4 x, float4 y, f16x8& h, f16x8& l)
{
    float v[8] = {x.x, x.y, x.z, x.w, y.x, y.y, y.z, y.w};
#pragma unroll
    for (int j = 0; j < 8; ++j) {
        h[j] = (_Float16)v[j];
        l[j] = (_Float16)((v[j] - (float)h[j]) * 1024.0f);
    }
}

__global__ __launch_bounds__(256) void gemm1_split(const float* __restrict__ A,
                                                   const _Float16* __restrict__ BhT,
                                                   const _Float16* __restrict__ BlT,
                                                   const float* __restrict__ bias,
                                                   float* __restrict__ Mout)
{
    __shared__ _Float16 Ah[128 * LSTR];
    __shared__ _Float16 Alo[128 * LSTR];
    __shared__ _Float16 Bh[128 * LSTR];
    __shared__ _Float16 Blo[128 * LSTR];
    const int tid = threadIdx.x;
    const int wave = tid >> 6, lane = tid & 63;
    const int wm = wave & 1, wn = wave >> 1;
    const int q = lane >> 4, ln = lane & 15;
    const int r0 = blockIdx.y * 128;   // slab-local row tile
    const int c0 = blockIdx.x * 128;   // col tile

    f32x4 acch[4][4] = {{{0.f,0.f,0.f,0.f}}};
    f32x4 accc[4][4] = {{{0.f,0.f,0.f,0.f}}};

    const int sr = tid >> 2, sc = tid & 3;     // staging row 0..63, k-chunk 0..3
    const float*    Ag  = A   + (size_t)(r0 + sr) * HIDd + sc * 8;
    const _Float16* Bhg = BhT + (size_t)(c0 + sr) * HIDd + sc * 8;
    const _Float16* Blg = BlT + (size_t)(c0 + sr) * HIDd + sc * 8;
    _Float16* Ahw = &Ah [sr * LSTR + sc * 8];
    _Float16* Alw = &Alo[sr * LSTR + sc * 8];
    _Float16* Bhw = &Bh [sr * LSTR + sc * 8];
    _Float16* Blw = &Blo[sr * LSTR + sc * 8];

    for (int k0 = 0; k0 < HIDd; k0 += 32) {
        // global loads first (hide latency across the barrier)
        const float4 a00 = *(const float4*)(Ag + k0);
        const float4 a01 = *(const float4*)(Ag + k0 + 4);
        const float4 a10 = *(const float4*)(Ag + (size_t)64 * HIDd + k0);
        const float4 a11 = *(const float4*)(Ag + (size_t)64 * HIDd + k0 + 4);
        const f16x8 bh0 = *(const f16x8*)(Bhg + k0);
        const f16x8 bh1 = *(const f16x8*)(Bhg + (size_t)64 * HIDd + k0);
        const f16x8 bl0 = *(const f16x8*)(Blg + k0);
        const f16x8 bl1 = *(const f16x8*)(Blg + (size_t)64 * HIDd + k0);
        f16x8 h0, l0, h1, l1;
        split8(a00, a01, h0, l0);
        split8(a10, a11, h1, l1);
        __syncthreads();
        *(f16x8*)(Ahw)             = h0;
        *(f16x8*)(Ahw + 64 * LSTR) = h1;
        *(f16x8*)(Alw)             = l0;
        *(f16x8*)(Alw + 64 * LSTR) = l1;
        *(f16x8*)(Bhw)             = bh0;
        *(f16x8*)(Bhw + 64 * LSTR) = bh1;
        *(f16x8*)(Blw)             = bl0;
        *(f16x8*)(Blw + 64 * LSTR) = bl1;
        __syncthreads();

        f16x8 fah[4], fal[4], fbh[4], fbl[4];
#pragma unroll
        for (int mt = 0; mt < 4; ++mt) {
            const int row = (wm * 64 + mt * 16 + ln) * LSTR + q * 8;
            fah[mt] = *(const f16x8*)&Ah [row];
            fal[mt] = *(const f16x8*)&Alo[row];
        }
#pragma unroll
        for (int nt = 0; nt < 4; ++nt) {
            const int row = (wn * 64 + nt * 16 + ln) * LSTR + q * 8;
            fbh[nt] = *(const f16x8*)&Bh [row];
            fbl[nt] = *(const f16x8*)&Blo[row];
        }
#pragma unroll
        for (int mt = 0; mt < 4; ++mt)
#pragma unroll
            for (int nt = 0; nt < 4; ++nt) {
                acch[mt][nt] = __builtin_amdgcn_mfma_f32_16x16x32_f16(fah[mt], fbh[nt], acch[mt][nt], 0, 0, 0);
                accc[mt][nt] = __builtin_amdgcn_mfma_f32_16x16x32_f16(fah[mt], fbl[nt], accc[mt][nt], 0, 0, 0);
                accc[mt][nt] = __builtin_amdgcn_mfma_f32_16x16x32_f16(fal[mt], fbh[nt], accc[mt][nt], 0, 0, 0);
            }
    }

    // epilogue: C/D layout col=lane&15, row=q*4+reg; combine hh + cross/1024 + bias; scatter
#pragma unroll
    for (int nt = 0; nt < 4; ++nt) {
        const int c = c0 + wn * 64 + nt * 16 + ln;
        const float bv = bias[c];
        const int h = c >> 8, e = c & 255;
#pragma unroll
        for (int mt = 0; mt < 4; ++mt) {
#pragma unroll
            for (int r = 0; r < 4; ++r) {
                const int row = r0 + wm * 64 + mt * 16 + q * 4 + r;
                const int bbl = row >> 11, t = row & 2047;
                Mout[((size_t)(bbl * 16 + h) * Tdim + t) * 256 + e] =
                    acch[mt][nt][r] + accc[mt][nt][r] * (1.0f / 1024.0f) + bv;
            }
        }
    }
}

// ---------------- Stage A: per-chunk products, both directions, one wave per (seq,chunk) --
__global__ __launch_bounds__(256) void stageA_kernel(const float* __restrict__ m,
                                                     float* __restrict__ q, int SS)
{
    __shared__ float Msh[4][256];
    const int tid = threadIdx.x;
    const int w = tid >> 6, lane = tid & 63;
    const int chain = blockIdx.x * 4 + w;          // (seq_local, c)
    const int seq = chain >> 6, c = chain & (Cn - 1);
    const int g = lane >> 4, j = lane & 15;

    float qlr[4], qrt[4];
#pragma unroll
    for (int a = 0; a < 4; ++a) {
        const float iv = (4 * g + a == j) ? 1.0f : 0.0f;
        qlr[a] = iv; qrt[a] = iv;
    }
    const float* mp = m + ((size_t)seq * Tdim + c * Ln) * 256 + lane * 4;
    float* sh = &Msh[w][0];

    for (int s = 0; s < Ln; ++s) {
        const float4 mv = *(const float4*)(mp + (size_t)s * 256);
        __syncthreads();
        *(float4*)&sh[lane * 4] = mv;
        __syncthreads();
        float qn[4]  = {0.f, 0.f, 0.f, 0.f};
        float qtn[4] = {0.f, 0.f, 0.f, 0.f};
#pragma unroll
        for (int kcl = 0; kcl < 4; ++kcl) {
            const int kc = (kcl + g) & 3;          // group-rotated: bank-conflict-free
            const float4 row0 = *(const float4*)&sh[(4 * g + 0) * 16 + 4 * kc];
            const float4 row1 = *(const float4*)&sh[(4 * g + 1) * 16 + 4 * kc];
            const float4 row2 = *(const float4*)&sh[(4 * g + 2) * 16 + 4 * kc];
            const float4 row3 = *(const float4*)&sh[(4 * g + 3) * 16 + 4 * kc];
#pragma unroll
            for (int bk = 0; bk < 4; ++bk) {
                const int k = 4 * kc + bk;
                const int src = (kc << 4) | j;
                const float qk  = __shfl(qlr[bk], src);   // Q[k][j]
                const float qtk = __shfl(qrt[bk], src);   // QrlT[k][j]
                const float4 mc = *(const float4*)&sh[k * 16 + 4 * g];
                qn[0] = fmaf((&row0.x)[bk], qk, qn[0]);
                qn[1] = fmaf((&row1.x)[bk], qk, qn[1]);
                qn[2] = fmaf((&row2.x)[bk], qk, qn[2]);
                qn[3] = fmaf((&row3.x)[bk], qk, qn[3]);
                qtn[0] = fmaf(mc.x, qtk, qtn[0]);
                qtn[1] = fmaf(mc.y, qtk, qtn[1]);
                qtn[2] = fmaf(mc.z, qtk, qtn[2]);
                qtn[3] = fmaf(mc.w, qtk, qtn[3]);
            }
        }
#pragma unroll
        for (int a = 0; a < 4; ++a) { qlr[a] = qn[a]; qrt[a] = qtn[a]; }
    }
    float ss = qlr[0]*qlr[0] + qlr[1]*qlr[1] + qlr[2]*qlr[2] + qlr[3]*qlr[3];
    float st = qrt[0]*qrt[0] + qrt[1]*qrt[1] + qrt[2]*qrt[2] + qrt[3]*qrt[3];
#pragma unroll
    for (int off = 1; off < 64; off <<= 1) { ss += __shfl_xor(ss, off); st += __shfl_xor(st, off); }
    const float sl = 1.0f / (sqrtf(ss) + 1e-30f);
    const float sr = 1.0f / (sqrtf(st) + 1e-30f);
    float* qlr_out = q + ((size_t)seq * Cn + c) * 256;
    float* qrl_out = q + ((size_t)(SS + seq) * Cn + c) * 256;
#pragma unroll
    for (int a = 0; a < 4; ++a) qlr_out[(4 * g + a) * 16 + j] = qlr[a] * sl;
    float4 qv; qv.x = qrt[0]*sr; qv.y = qrt[1]*sr; qv.z = qrt[2]*sr; qv.w = qrt[3]*sr;
    *(float4*)(qrl_out + j * 16 + 4 * g) = qv;     // QrlT -> Qrl transposed store
}

// ---------------- Stage B: cross-chunk vector propagation --------------------------------
__global__ __launch_bounds__(64) void stageB_kernel(const float* __restrict__ q,
                                                    float* __restrict__ vs, int SS)
{
    const int lane = threadIdx.x & 63;
    const int i = lane & 15;
    const int chain = blockIdx.x;                  // 0 .. 2*SS-1
    const int dir = (chain >= SS) ? 1 : 0;
    const int seq = chain - dir * SS;
    const float* qb = q + (size_t)(dir * SS + seq) * Cn * 256;
    float* vb = vs + (size_t)(dir * SS + seq) * Cn * 16;

    float myw = (i == 0) ? 1.0f : 0.0f;
    float wv[16];
#pragma unroll
    for (int k2 = 0; k2 < 16; ++k2) wv[k2] = (k2 == 0) ? 1.0f : 0.0f;

    for (int s = 0; s < Cn; ++s) {
        const int cc = dir ? (Cn - 1 - s) : s;
        vb[cc * 16 + i] = myw;
        const float* Qp = qb + (size_t)cc * 256 + i * 16;
        const float4 q0 = *(const float4*)(Qp + 0);
        const float4 q1 = *(const float4*)(Qp + 4);
        const float4 q2 = *(const float4*)(Qp + 8);
        const float4 q3 = *(const float4*)(Qp + 12);
        float nv = q0.x*wv[0] + q0.y*wv[1] + q0.z*wv[2] + q0.w*wv[3]
                 + q1.x*wv[4] + q1.y*wv[5] + q1.z*wv[6] + q1.w*wv[7]
                 + q2.x*wv[8] + q2.y*wv[9] + q2.z*wv[10] + q2.w*wv[11]
                 + q3.x*wv[12] + q3.y*wv[13] + q3.z*wv[14] + q3.w*wv[15];
        float s2 = nv * nv;
        s2 += __shfl_xor(s2, 1); s2 += __shfl_xor(s2, 2);
        s2 += __shfl_xor(s2, 4); s2 += __shfl_xor(s2, 8);
        const float wn = nv / (sqrtf(s2) + 1e-20f);
        myw = wn;
#pragma unroll
        for (int k2 = 0; k2 < 16; ++k2) wv[k2] = __shfl(wn, (lane & 48) | k2);
    }
}

// ---------------- Stage C: per-step history with exact reference eps semantics ------------
__global__ __launch_bounds__(256) void stageC_kernel(const float* __restrict__ m,
                                                     const float* __restrict__ vs,
                                                     float* __restrict__ x, int SS)
{
    const int tid = threadIdx.x;
    const int lane = tid & 63;
    const int i = lane & 15;
    const int chain = blockIdx.x * 16 + (tid >> 4);
    const int dir = chain & 1;
    const int sc = chain >> 1;
    const int c = sc & (Cn - 1), seq = sc >> 6;
    const int bbl = seq >> 4, h = seq & 15;

    const float* vp = vs + ((size_t)(dir * SS + seq) * Cn + c) * 16;
    float vv[16];
#pragma unroll
    for (int k2 = 0; k2 < 16; ++k2) vv[k2] = vp[k2];

    const int t0 = c * Ln;
    for (int s = 0; s < Ln; ++s) {
        const int t = dir ? (t0 + Ln - 1 - s) : (t0 + s);
        const float* Mp = m + ((size_t)seq * Tdim + t) * 256 + i * 16;
        const float4 r0 = *(const float4*)(Mp + 0);
        const float4 r1 = *(const float4*)(Mp + 4);
        const float4 r2 = *(const float4*)(Mp + 8);
        const float4 r3 = *(const float4*)(Mp + 12);
        float nv = r0.x*vv[0] + r0.y*vv[1] + r0.z*vv[2] + r0.w*vv[3]
                 + r1.x*vv[4] + r1.y*vv[5] + r1.z*vv[6] + r1.w*vv[7]
                 + r2.x*vv[8] + r2.y*vv[9] + r2.z*vv[10] + r2.w*vv[11]
                 + r3.x*vv[12] + r3.y*vv[13] + r3.z*vv[14] + r3.w*vv[15];
        float s2 = nv * nv;
        s2 += __shfl_xor(s2, 1); s2 += __shfl_xor(s2, 2);
        s2 += __shfl_xor(s2, 4); s2 += __shfl_xor(s2, 8);
        const float vn = nv / (sqrtf(s2) + 1e-6f);     // reference VEC_EPS semantics
        x[(((size_t)bbl * Tdim + t) * NHd + h) * 32 + dir * 16 + i] = vn;
#pragma unroll
        for (int k2 = 0; k2 < 16; ++k2) vv[k2] = __shfl(vn, (lane & 48) | k2);
    }
}

// ---------------- GEMM2: out = gelu(x @ W_out + b_out), exact erf gelu --------------------
__global__ __launch_bounds__(256) void gemm2_kernel(const float* __restrict__ A,
                                                    const float* __restrict__ W,
                                                    const float* __restrict__ bias,
                                                    float* __restrict__ out, int row0)
{
    __shared__ float As[16][128];
    __shared__ float Bs[16][128];
    const int tid = threadIdx.x;
    const int r0 = blockIdx.y * 128;
    const int c0 = blockIdx.x * 128;
    const int ty = tid >> 4, tx = tid & 15;
    const int a_row = tid >> 1, a_col = (tid & 1) * 8;
    const int b_row = tid >> 4, b_col = (tid & 15) * 8;

    float acc[8][8];
#pragma unroll
    for (int i = 0; i < 8; ++i)
#pragma unroll
        for (int j = 0; j < 8; ++j) acc[i][j] = 0.f;

    const float* Aptr = A + (size_t)(r0 + a_row) * 512 + a_col;
    const float* Wptr = W + (size_t)b_row * 1024 + c0 + b_col;

    for (int kk = 0; kk < 512; kk += 16) {
        float4 av0 = *(const float4*)(Aptr + kk);
        float4 av1 = *(const float4*)(Aptr + kk + 4);
        float4 bv0 = *(const float4*)(Wptr + (size_t)kk * 1024);
        float4 bv1 = *(const float4*)(Wptr + (size_t)kk * 1024 + 4);
        __syncthreads();
        As[a_col + 0][a_row] = av0.x;
        As[a_col + 1][a_row] = av0.y;
        As[a_col + 2][a_row] = av0.z;
        As[a_col + 3][a_row] = av0.w;
        As[a_col + 4][a_row] = av1.x;
        As[a_col + 5][a_row] = av1.y;
        As[a_col + 6][a_row] = av1.z;
        As[a_col + 7][a_row] = av1.w;
        *(float4*)&Bs[b_row][b_col]     = bv0;
        *(float4*)&Bs[b_row][b_col + 4] = bv1;
        __syncthreads();
#pragma unroll
        for (int k = 0; k < 16; ++k) {
            float a[8], b[8];
            *(float4*)&a[0] = *(const float4*)&As[k][ty * 8];
            *(float4*)&a[4] = *(const float4*)&As[k][ty * 8 + 4];
            *(float4*)&b[0] = *(const float4*)&Bs[k][tx * 8];
            *(float4*)&b[4] = *(const float4*)&Bs[k][tx * 8 + 4];
#pragma unroll
            for (int i = 0; i < 8; ++i)
#pragma unroll
                for (int j = 0; j < 8; ++j)
                    acc[i][j] = fmaf(a[i], b[j], acc[i][j]);
        }
    }
#pragma unroll
    for (int i = 0; i < 8; ++i) {
        const int r = r0 + ty * 8 + i;
#pragma unroll
        for (int jj = 0; jj < 8; jj += 4) {
            const int c = c0 + tx * 8 + jj;
            float4 v;
            v.x = acc[i][jj + 0] + bias[c + 0];
            v.y = acc[i][jj + 1] + bias[c + 1];
            v.z = acc[i][jj + 2] + bias[c + 2];
            v.w = acc[i][jj + 3] + bias[c + 3];
            v.x = 0.5f * v.x * (1.0f + erff(v.x * 0.70710678118654752f));
            v.y = 0.5f * v.y * (1.0f + erff(v.y * 0.70710678118654752f));
            v.z = 0.5f * v.z * (1.0f + erff(v.z * 0.70710678118654752f));
            v.w = 0.5f * v.w * (1.0f + erff(v.w * 0.70710678118654752f));
            *(float4*)(out + (size_t)(row0 + r) * 1024 + c) = v;
        }
    }
}

extern "C" void kernel_launch(void* const* d_in, const int* in_sizes, int n_in,
                              void* d_out, int out_size, void* d_ws, size_t ws_size,
                              hipStream_t stream)
{
    const float* hs    = (const float*)d_in[0];
    const float* W_mat = (const float*)d_in[1];
    const float* b_mat = (const float*)d_in[2];
    const float* W_out = (const float*)d_in[3];
    const float* b_out = (const float*)d_in[4];
    float* out = (float*)d_out;

    // per-batch: m fp32 (32 MB) + qx (4 MB) + vs (128 KB); global: W planes (16 MB)
    const size_t per_bb = (32ull << 20) + (4ull << 20) + (128ull << 10); // 37,879,808 B
    const size_t wbase  = 16ull << 20;
    int nbb = 8;
    while (nbb > 1 && ws_size < wbase + (size_t)nbb * per_bb) nbb >>= 1;

    char* base = (char*)d_ws;
    _Float16* WhT = (_Float16*)base;
    _Float16* WlT = (_Float16*)(base + (8ull << 20));
    size_t off = wbase;
    float* m  = (float*)(base + off);  off += (size_t)nbb * (32ull << 20);
    float* qx = (float*)(base + off);  off += (size_t)nbb * (4ull << 20);
    float* vs = (float*)(base + off);

    conv_WT_kernel<<<dim3(128, 32), 256, 0, stream>>>(W_mat, WhT, WlT);

    for (int bb0 = 0; bb0 < 8; bb0 += nbb) {
        const int row0 = bb0 * Tdim;
        const int SS = nbb * 16;
        gemm1_split<<<dim3(32, nbb * 16), 256, 0, stream>>>(
            hs + (size_t)row0 * HIDd, WhT, WlT, b_mat, m);
        stageA_kernel<<<nbb * 256, 256, 0, stream>>>(m, qx, SS);
        stageB_kernel<<<nbb * 32, 64, 0, stream>>>(qx, vs, SS);
        stageC_kernel<<<nbb * 128, 256, 0, stream>>>(m, vs, qx, SS);
        gemm2_kernel<<<dim3(8, SS), 256, 0, stream>>>(qx, W_out, b_out, out, row0);
    }
}

// Round 5
// 1265.392 us; speedup vs baseline: 1.6864x; 1.1679x over previous
//
#include <hip/hip_runtime.h>
#include <math.h>

#define Tdim 2048
#define HIDd 1024
#define NHd 16
#define NCOL 4096         // NH*16*16
#define Cn 64             // chunks per sequence
#define Ln 32             // chunk length (Cn*Ln == Tdim)
#define LSTR 40           // f16 elems per LDS row (80 B): bank-friendly pad

typedef _Float16 f16x4  __attribute__((ext_vector_type(4)));
typedef _Float16 f16x8  __attribute__((ext_vector_type(8)));
typedef float    f32x4  __attribute__((ext_vector_type(4)));

// ---------------- W_mat (1024 x 4096 fp32) -> WhT / WlT (4096 x 1024 fp16, lo x1024) -----
__global__ __launch_bounds__(256) void conv_WT_kernel(const float* __restrict__ W,
                                                      _Float16* __restrict__ WhT,
                                                      _Float16* __restrict__ WlT)
{
    __shared__ float t[32][33];
    const int tx = threadIdx.x & 31, ty = threadIdx.x >> 5;   // ty 0..7
    const int n0 = blockIdx.x * 32, k0 = blockIdx.y * 32;
#pragma unroll
    for (int i = 0; i < 4; ++i)
        t[ty + i * 8][tx] = W[(size_t)(k0 + ty + i * 8) * NCOL + n0 + tx];
    __syncthreads();
#pragma unroll
    for (int i = 0; i < 4; ++i) {
        const float w = t[tx][ty + i * 8];
        const _Float16 h = (_Float16)w;
        const size_t o = (size_t)(n0 + ty + i * 8) * HIDd + k0 + tx;
        WhT[o] = h;
        WlT[o] = (_Float16)((w - (float)h) * 1024.0f);
    }
}

// ---------------- W_out (512 x 1024 fp32) -> W2T (1024 x 512 fp16) ------------------------
__global__ __launch_bounds__(256) void conv_W2T_kernel(const float* __restrict__ W,
                                                       _Float16* __restrict__ WT)
{
    __shared__ float t[32][33];
    const int tx = threadIdx.x & 31, ty = threadIdx.x >> 5;
    const int n0 = blockIdx.x * 32, k0 = blockIdx.y * 32;
#pragma unroll
    for (int i = 0; i < 4; ++i)
        t[ty + i * 8][tx] = W[(size_t)(k0 + ty + i * 8) * 1024 + n0 + tx];
    __syncthreads();
#pragma unroll
    for (int i = 0; i < 4; ++i)
        WT[(size_t)(n0 + ty + i * 8) * 512 + k0 + tx] = (_Float16)t[tx][ty + i * 8];
}

// ---------------- GEMM1 (split-f16 MFMA): m = hs @ W_mat + b_mat -> fp32, scattered -------
__device__ inline void split8(float4 x, float4 y, f16x8& h, f16x8& l)
{
    float v[8] = {x.x, x.y, x.z, x.w, y.x, y.y, y.z, y.w};
#pragma unroll
    for (int j = 0; j < 8; ++j) {
        h[j] = (_Float16)v[j];
        l[j] = (_Float16)((v[j] - (float)h[j]) * 1024.0f);
    }
}

__global__ __launch_bounds__(256) void gemm1_split(const float* __restrict__ A,
                                                   const _Float16* __restrict__ BhT,
                                                   const _Float16* __restrict__ BlT,
                                                   const float* __restrict__ bias,
                                                   float* __restrict__ Mout)
{
    __shared__ _Float16 Ah[128 * LSTR];
    __shared__ _Float16 Alo[128 * LSTR];
    __shared__ _Float16 Bh[128 * LSTR];
    __shared__ _Float16 Blo[128 * LSTR];
    const int tid = threadIdx.x;
    const int wave = tid >> 6, lane = tid & 63;
    const int wm = wave & 1, wn = wave >> 1;
    const int q = lane >> 4, ln = lane & 15;
    const int r0 = blockIdx.y * 128;
    const int c0 = blockIdx.x * 128;

    f32x4 acch[4][4] = {{{0.f,0.f,0.f,0.f}}};
    f32x4 accc[4][4] = {{{0.f,0.f,0.f,0.f}}};

    const int sr = tid >> 2, sc = tid & 3;
    const float*    Ag  = A   + (size_t)(r0 + sr) * HIDd + sc * 8;
    const _Float16* Bhg = BhT + (size_t)(c0 + sr) * HIDd + sc * 8;
    const _Float16* Blg = BlT + (size_t)(c0 + sr) * HIDd + sc * 8;
    _Float16* Ahw = &Ah [sr * LSTR + sc * 8];
    _Float16* Alw = &Alo[sr * LSTR + sc * 8];
    _Float16* Bhw = &Bh [sr * LSTR + sc * 8];
    _Float16* Blw = &Blo[sr * LSTR + sc * 8];

    for (int k0 = 0; k0 < HIDd; k0 += 32) {
        const float4 a00 = *(const float4*)(Ag + k0);
        const float4 a01 = *(const float4*)(Ag + k0 + 4);
        const float4 a10 = *(const float4*)(Ag + (size_t)64 * HIDd + k0);
        const float4 a11 = *(const float4*)(Ag + (size_t)64 * HIDd + k0 + 4);
        const f16x8 bh0 = *(const f16x8*)(Bhg + k0);
        const f16x8 bh1 = *(const f16x8*)(Bhg + (size_t)64 * HIDd + k0);
        const f16x8 bl0 = *(const f16x8*)(Blg + k0);
        const f16x8 bl1 = *(const f16x8*)(Blg + (size_t)64 * HIDd + k0);
        f16x8 h0, l0, h1, l1;
        split8(a00, a01, h0, l0);
        split8(a10, a11, h1, l1);
        __syncthreads();
        *(f16x8*)(Ahw)             = h0;
        *(f16x8*)(Ahw + 64 * LSTR) = h1;
        *(f16x8*)(Alw)             = l0;
        *(f16x8*)(Alw + 64 * LSTR) = l1;
        *(f16x8*)(Bhw)             = bh0;
        *(f16x8*)(Bhw + 64 * LSTR) = bh1;
        *(f16x8*)(Blw)             = bl0;
        *(f16x8*)(Blw + 64 * LSTR) = bl1;
        __syncthreads();

        f16x8 fah[4], fal[4], fbh[4], fbl[4];
#pragma unroll
        for (int mt = 0; mt < 4; ++mt) {
            const int row = (wm * 64 + mt * 16 + ln) * LSTR + q * 8;
            fah[mt] = *(const f16x8*)&Ah [row];
            fal[mt] = *(const f16x8*)&Alo[row];
        }
#pragma unroll
        for (int nt = 0; nt < 4; ++nt) {
            const int row = (wn * 64 + nt * 16 + ln) * LSTR + q * 8;
            fbh[nt] = *(const f16x8*)&Bh [row];
            fbl[nt] = *(const f16x8*)&Blo[row];
        }
#pragma unroll
        for (int mt = 0; mt < 4; ++mt)
#pragma unroll
            for (int nt = 0; nt < 4; ++nt) {
                acch[mt][nt] = __builtin_amdgcn_mfma_f32_16x16x32_f16(fah[mt], fbh[nt], acch[mt][nt], 0, 0, 0);
                accc[mt][nt] = __builtin_amdgcn_mfma_f32_16x16x32_f16(fah[mt], fbl[nt], accc[mt][nt], 0, 0, 0);
                accc[mt][nt] = __builtin_amdgcn_mfma_f32_16x16x32_f16(fal[mt], fbh[nt], accc[mt][nt], 0, 0, 0);
            }
    }
#pragma unroll
    for (int nt = 0; nt < 4; ++nt) {
        const int c = c0 + wn * 64 + nt * 16 + ln;
        const float bv = bias[c];
        const int h = c >> 8, e = c & 255;
#pragma unroll
        for (int mt = 0; mt < 4; ++mt) {
#pragma unroll
            for (int r = 0; r < 4; ++r) {
                const int row = r0 + wm * 64 + mt * 16 + q * 4 + r;
                const int bbl = row >> 11, t = row & 2047;
                Mout[((size_t)(bbl * 16 + h) * Tdim + t) * 256 + e] =
                    acch[mt][nt][r] + accc[mt][nt][r] * (1.0f / 1024.0f) + bv;
            }
        }
    }
}

// ---------------- Stage A (MFMA chain): per-chunk products, one wave per (seq,c) ----------
// D-layout of mfma_f32_16x16x16f16 == its B-operand layout, so Q<-M*Q chains shuffle-free.
// lr: Q <- M*Q (A = M); rl (transposed product): Qt <- M^T*Qt (A = M^T).
__global__ __launch_bounds__(256) void stageA_mfma(const float* __restrict__ m,
                                                   float* __restrict__ q, int SS)
{
    const int tid = threadIdx.x;
    const int wave = tid >> 6, lane = tid & 63;
    const int qd = lane >> 4, ln = lane & 15;
    const int chain = blockIdx.x * 4 + wave;
    const int seq = chain >> 6, c = chain & (Cn - 1);
    const float* mp = m + ((size_t)seq * Tdim + c * Ln) * 256;

    float vlr[4], vrl[4];                 // running products, fp32, B/D layout
#pragma unroll
    for (int r = 0; r < 4; ++r) {
        const float iv = (qd * 4 + r == ln) ? 1.0f : 0.0f;
        vlr[r] = iv; vrl[r] = iv;
    }

    for (int s = 0; s < Ln; ++s) {
        const float* Ms = mp + s * 256;
        const float4 arow = *(const float4*)(Ms + ln * 16 + qd * 4);  // M[ln][4qd..+3]
        float acol[4];
#pragma unroll
        for (int i = 0; i < 4; ++i) acol[i] = Ms[(4 * qd + i) * 16 + ln]; // M[4qd+i][ln]

        // Frobenius scale: arow covers each matrix entry exactly once across the wave
        float f2 = arow.x*arow.x + arow.y*arow.y + arow.z*arow.z + arow.w*arow.w;
#pragma unroll
        for (int off = 1; off < 64; off <<= 1) f2 += __shfl_xor(f2, off);
        const float sm = 4.0f * rsqrtf(f2 + 1e-12f);

        // split M fragments (hi + lo*1024)
        f16x4 mhr, mlr2, mhc, mlc;
        const float ar[4] = {arow.x * sm, arow.y * sm, arow.z * sm, arow.w * sm};
#pragma unroll
        for (int i = 0; i < 4; ++i) {
            _Float16 h = (_Float16)ar[i];
            mhr[i] = h; mlr2[i] = (_Float16)((ar[i] - (float)h) * 1024.0f);
            const float v = acol[i] * sm;
            h = (_Float16)v;
            mhc[i] = h; mlc[i] = (_Float16)((v - (float)h) * 1024.0f);
        }
        // split Q operands
        f16x4 qh1, ql1, qh2, ql2;
#pragma unroll
        for (int r = 0; r < 4; ++r) {
            _Float16 h = (_Float16)vlr[r];
            qh1[r] = h; ql1[r] = (_Float16)((vlr[r] - (float)h) * 1024.0f);
            h = (_Float16)vrl[r];
            qh2[r] = h; ql2[r] = (_Float16)((vrl[r] - (float)h) * 1024.0f);
        }
        f32x4 a1 = {0.f,0.f,0.f,0.f}, a2 = {0.f,0.f,0.f,0.f};
        f32x4 b1 = {0.f,0.f,0.f,0.f}, b2 = {0.f,0.f,0.f,0.f};
        a1 = __builtin_amdgcn_mfma_f32_16x16x16f16(mhr,  qh1, a1, 0, 0, 0);
        a2 = __builtin_amdgcn_mfma_f32_16x16x16f16(mhr,  ql1, a2, 0, 0, 0);
        a2 = __builtin_amdgcn_mfma_f32_16x16x16f16(mlr2, qh1, a2, 0, 0, 0);
        b1 = __builtin_amdgcn_mfma_f32_16x16x16f16(mhc,  qh2, b1, 0, 0, 0);
        b2 = __builtin_amdgcn_mfma_f32_16x16x16f16(mhc,  ql2, b2, 0, 0, 0);
        b2 = __builtin_amdgcn_mfma_f32_16x16x16f16(mlc,  qh2, b2, 0, 0, 0);

        float mx1 = 0.f, mx2 = 0.f;
#pragma unroll
        for (int r = 0; r < 4; ++r) {
            vlr[r] = a1[r] + a2[r] * (1.0f / 1024.0f);
            vrl[r] = b1[r] + b2[r] * (1.0f / 1024.0f);
            mx1 = fmaxf(mx1, fabsf(vlr[r]));
            mx2 = fmaxf(mx2, fabsf(vrl[r]));
        }
#pragma unroll
        for (int off = 1; off < 64; off <<= 1) {
            mx1 = fmaxf(mx1, __shfl_xor(mx1, off));
            mx2 = fmaxf(mx2, __shfl_xor(mx2, off));
        }
        const float i1 = 1.0f / (mx1 + 1e-30f);   // positive rescale: projectively legal,
        const float i2 = 1.0f / (mx2 + 1e-30f);   // keeps f16 split planes in normal range
#pragma unroll
        for (int r = 0; r < 4; ++r) { vlr[r] *= i1; vrl[r] *= i2; }
    }

    float ss = 0.f, st = 0.f;
#pragma unroll
    for (int r = 0; r < 4; ++r) { ss += vlr[r]*vlr[r]; st += vrl[r]*vrl[r]; }
#pragma unroll
    for (int off = 1; off < 64; off <<= 1) { ss += __shfl_xor(ss, off); st += __shfl_xor(st, off); }
    const float sl = 1.0f / (sqrtf(ss) + 1e-30f);
    const float sr = 1.0f / (sqrtf(st) + 1e-30f);
    float* qlr_out = q + ((size_t)seq * Cn + c) * 256;
    float* qrl_out = q + ((size_t)(SS + seq) * Cn + c) * 256;
#pragma unroll
    for (int r = 0; r < 4; ++r)
        qlr_out[(qd * 4 + r) * 16 + ln] = vlr[r] * sl;   // Qlr[row][col]
    float4 qv; qv.x = vrl[0]*sr; qv.y = vrl[1]*sr; qv.z = vrl[2]*sr; qv.w = vrl[3]*sr;
    *(float4*)(qrl_out + ln * 16 + qd * 4) = qv;         // Qt holds P^T -> store P
}

// ---------------- Stage B: cross-chunk vector propagation --------------------------------
__global__ __launch_bounds__(64) void stageB_kernel(const float* __restrict__ q,
                                                    float* __restrict__ vs, int SS)
{
    const int lane = threadIdx.x & 63;
    const int i = lane & 15;
    const int chain = blockIdx.x;
    const int dir = (chain >= SS) ? 1 : 0;
    const int seq = chain - dir * SS;
    const float* qb = q + (size_t)(dir * SS + seq) * Cn * 256;
    float* vb = vs + (size_t)(dir * SS + seq) * Cn * 16;

    float myw = (i == 0) ? 1.0f : 0.0f;
    float wv[16];
#pragma unroll
    for (int k2 = 0; k2 < 16; ++k2) wv[k2] = (k2 == 0) ? 1.0f : 0.0f;

    for (int s = 0; s < Cn; ++s) {
        const int cc = dir ? (Cn - 1 - s) : s;
        vb[cc * 16 + i] = myw;
        const float* Qp = qb + (size_t)cc * 256 + i * 16;
        const float4 q0 = *(const float4*)(Qp + 0);
        const float4 q1 = *(const float4*)(Qp + 4);
        const float4 q2 = *(const float4*)(Qp + 8);
        const float4 q3 = *(const float4*)(Qp + 12);
        float nv = q0.x*wv[0] + q0.y*wv[1] + q0.z*wv[2] + q0.w*wv[3]
                 + q1.x*wv[4] + q1.y*wv[5] + q1.z*wv[6] + q1.w*wv[7]
                 + q2.x*wv[8] + q2.y*wv[9] + q2.z*wv[10] + q2.w*wv[11]
                 + q3.x*wv[12] + q3.y*wv[13] + q3.z*wv[14] + q3.w*wv[15];
        float s2 = nv * nv;
        s2 += __shfl_xor(s2, 1); s2 += __shfl_xor(s2, 2);
        s2 += __shfl_xor(s2, 4); s2 += __shfl_xor(s2, 8);
        const float wn = nv / (sqrtf(s2) + 1e-20f);
        myw = wn;
#pragma unroll
        for (int k2 = 0; k2 < 16; ++k2) wv[k2] = __shfl(wn, (lane & 48) | k2);
    }
}

// ---------------- Stage C: per-step history, LDS broadcast, f16 x output ------------------
__global__ __launch_bounds__(256) void stageC_kernel(const float* __restrict__ m,
                                                     const float* __restrict__ vs,
                                                     _Float16* __restrict__ x, int SS)
{
    __shared__ float vbuf[16][16];
    const int tid = threadIdx.x;
    const int lane = tid & 63;
    const int j = lane & 15;
    const int grp = tid >> 4;                   // chain slot in block (wave-private groups)
    const int chain = blockIdx.x * 16 + grp;
    const int dir = chain & 1;
    const int sc = chain >> 1;
    const int c = sc & (Cn - 1), seq = sc >> 6;
    const int bbl = seq >> 4, h = seq & 15;

    vbuf[grp][j] = vs[((size_t)(dir * SS + seq) * Cn + c) * 16 + j];

    const int t0 = c * Ln;
    for (int s = 0; s < Ln; ++s) {
        const int t = dir ? (t0 + Ln - 1 - s) : (t0 + s);
        const float* Mp = m + ((size_t)seq * Tdim + t) * 256 + j * 16;
        const float4 r0 = *(const float4*)(Mp + 0);
        const float4 r1 = *(const float4*)(Mp + 4);
        const float4 r2 = *(const float4*)(Mp + 8);
        const float4 r3 = *(const float4*)(Mp + 12);
        const float4 w0 = *(const float4*)&vbuf[grp][0];
        const float4 w1 = *(const float4*)&vbuf[grp][4];
        const float4 w2 = *(const float4*)&vbuf[grp][8];
        const float4 w3 = *(const float4*)&vbuf[grp][12];
        float nv = r0.x*w0.x + r0.y*w0.y + r0.z*w0.z + r0.w*w0.w
                 + r1.x*w1.x + r1.y*w1.y + r1.z*w1.z + r1.w*w1.w
                 + r2.x*w2.x + r2.y*w2.y + r2.z*w2.z + r2.w*w2.w
                 + r3.x*w3.x + r3.y*w3.y + r3.z*w3.z + r3.w*w3.w;
        float s2 = nv * nv;
        s2 += __shfl_xor(s2, 1); s2 += __shfl_xor(s2, 2);
        s2 += __shfl_xor(s2, 4); s2 += __shfl_xor(s2, 8);
        const float vn = nv / (sqrtf(s2) + 1e-6f);     // reference VEC_EPS semantics
        x[(((size_t)bbl * Tdim + t) * NHd + h) * 32 + dir * 16 + j] = (_Float16)vn;
        vbuf[grp][j] = vn;                             // wave-private: no barrier needed
    }
}

// ---------------- GEMM2 (f16 MFMA): out = gelu(x @ W_out + b_out) -------------------------
__global__ __launch_bounds__(256) void gemm2_f16(const _Float16* __restrict__ A,
                                                 const _Float16* __restrict__ BT,
                                                 const float* __restrict__ bias,
                                                 float* __restrict__ out, int row0)
{
    __shared__ _Float16 Al[128 * LSTR];
    __shared__ _Float16 Bl[128 * LSTR];
    const int tid = threadIdx.x;
    const int wave = tid >> 6, lane = tid & 63;
    const int wm = wave & 1, wn = wave >> 1;
    const int qd = lane >> 4, ln = lane & 15;
    const int r0 = blockIdx.y * 128;
    const int c0 = blockIdx.x * 128;

    f32x4 acc[4][4] = {{{0.f,0.f,0.f,0.f}}};

    const int sr = tid >> 2, sc = tid & 3;
    const _Float16* Ag = A  + (size_t)(r0 + sr) * 512 + sc * 8;
    const _Float16* Bg = BT + (size_t)(c0 + sr) * 512 + sc * 8;
    _Float16* Alw = &Al[sr * LSTR + sc * 8];
    _Float16* Blw = &Bl[sr * LSTR + sc * 8];

    for (int k0 = 0; k0 < 512; k0 += 32) {
        const f16x8 a0 = *(const f16x8*)(Ag + k0);
        const f16x8 a1 = *(const f16x8*)(Ag + (size_t)64 * 512 + k0);
        const f16x8 b0 = *(const f16x8*)(Bg + k0);
        const f16x8 b1 = *(const f16x8*)(Bg + (size_t)64 * 512 + k0);
        __syncthreads();
        *(f16x8*)(Alw)             = a0;
        *(f16x8*)(Alw + 64 * LSTR) = a1;
        *(f16x8*)(Blw)             = b0;
        *(f16x8*)(Blw + 64 * LSTR) = b1;
        __syncthreads();
        f16x8 af[4], bf[4];
#pragma unroll
        for (int mt = 0; mt < 4; ++mt)
            af[mt] = *(const f16x8*)&Al[(wm * 64 + mt * 16 + ln) * LSTR + qd * 8];
#pragma unroll
        for (int nt = 0; nt < 4; ++nt)
            bf[nt] = *(const f16x8*)&Bl[(wn * 64 + nt * 16 + ln) * LSTR + qd * 8];
#pragma unroll
        for (int mt = 0; mt < 4; ++mt)
#pragma unroll
            for (int nt = 0; nt < 4; ++nt)
                acc[mt][nt] = __builtin_amdgcn_mfma_f32_16x16x32_f16(af[mt], bf[nt], acc[mt][nt], 0, 0, 0);
    }
#pragma unroll
    for (int nt = 0; nt < 4; ++nt) {
        const int c = c0 + wn * 64 + nt * 16 + ln;
        const float bv = bias[c];
#pragma unroll
        for (int mt = 0; mt < 4; ++mt) {
#pragma unroll
            for (int r = 0; r < 4; ++r) {
                const int row = r0 + wm * 64 + mt * 16 + qd * 4 + r;
                float v = acc[mt][nt][r] + bv;
                v = 0.5f * v * (1.0f + erff(v * 0.70710678118654752f));
                out[(size_t)(row0 + row) * 1024 + c] = v;
            }
        }
    }
}

extern "C" void kernel_launch(void* const* d_in, const int* in_sizes, int n_in,
                              void* d_out, int out_size, void* d_ws, size_t ws_size,
                              hipStream_t stream)
{
    const float* hs    = (const float*)d_in[0];
    const float* W_mat = (const float*)d_in[1];
    const float* b_mat = (const float*)d_in[2];
    const float* W_out = (const float*)d_in[3];
    const float* b_out = (const float*)d_in[4];
    float* out = (float*)d_out;

    // layout: WhT(8M) WlT(8M) W2T(1M) | m: nbb*32M | qx: nbb*2M (q fp32 / x f16 aliased) | vs
    const size_t per_bb = (32ull << 20) + (2ull << 20) + (128ull << 10);
    const size_t wbase  = 17ull << 20;
    int nbb = 8;
    while (nbb > 1 && ws_size < wbase + (size_t)nbb * per_bb) nbb >>= 1;

    char* base = (char*)d_ws;
    _Float16* WhT = (_Float16*)base;
    _Float16* WlT = (_Float16*)(base + (8ull << 20));
    _Float16* W2T = (_Float16*)(base + (16ull << 20));
    size_t off = wbase;
    float* m  = (float*)(base + off);  off += (size_t)nbb * (32ull << 20);
    float* qx = (float*)(base + off);  off += (size_t)nbb * (2ull << 20);
    float* vs = (float*)(base + off);

    conv_WT_kernel<<<dim3(128, 32), 256, 0, stream>>>(W_mat, WhT, WlT);
    conv_W2T_kernel<<<dim3(32, 16), 256, 0, stream>>>(W_out, W2T);

    for (int bb0 = 0; bb0 < 8; bb0 += nbb) {
        const int row0 = bb0 * Tdim;
        const int SS = nbb * 16;
        gemm1_split<<<dim3(32, nbb * 16), 256, 0, stream>>>(
            hs + (size_t)row0 * HIDd, WhT, WlT, b_mat, m);
        stageA_mfma<<<nbb * 256, 256, 0, stream>>>(m, qx, SS);
        stageB_kernel<<<nbb * 32, 64, 0, stream>>>(qx, vs, SS);
        stageC_kernel<<<nbb * 128, 256, 0, stream>>>(m, vs, (_Float16*)qx, SS);
        gemm2_f16<<<dim3(8, nbb * 16), 256, 0, stream>>>((_Float16*)qx, W2T, b_out, out, row0);
    }
}